// Round 21
// baseline (250.418 us; speedup 1.0000x reference)
//
#include <hip/hip_runtime.h>

#define N_NODES 100000
#define N_PAD   100096
#define N_EDGES 1600000
#define N_GRAPHS 1024
#define F_IN 74
#define HID 100

#define KP1 160   // W1: [self 0..73 | 0 | agg 80..153 | 0]; A from fbf(k<80)+agt(k>=80)
#define KP2 224   // W2: [self 0..99 | 0 100..111 | agg 112..211 | 0 212..223]

#define FBF_LD 80    // bf16 feats rows (160B)
#define F8T_LD 80    // fp8 feats rows (80B)
#define AGT_LD 80    // bf16 agg1 rows (160B)
#define AGT2_LD 112  // bf16 agg2 rows (224B, cols 100..111 zero)
#define H1C8_LD 128  // fp8 h1 compact rows (128B, cols 100..127 zero)
#define H2_LD  100   // bf16 h2 rows (200B)

#define ZROW N_NODES                 // zero-row index for degree padding

#define NB ((N_NODES + 255) / 256)   // 391 dst-buckets of 256 nodes
#define BKCAP 8192                   // bbuf/csr slots per bucket
#define BIN_EPB 4096                 // edges per binning block
#define NBB ((N_EDGES + BIN_EPB - 1) / BIN_EPB)

typedef __attribute__((ext_vector_type(8))) short short8;
typedef __attribute__((ext_vector_type(4))) float f32x4;
typedef __attribute__((ext_vector_type(2))) float f32x2;

#if defined(__has_builtin)
#if __has_builtin(__builtin_amdgcn_cvt_pk_f32_fp8) && __has_builtin(__builtin_amdgcn_cvt_pk_fp8_f32)
#define HAVE_FP8 1
#endif
#endif

__device__ __forceinline__ unsigned short f2bf(float x) {
    union { float f; unsigned u; } c; c.f = x;
    unsigned u = c.u;
    unsigned r = (u + 0x7fffu + ((u >> 16) & 1u)) >> 16;
    return (unsigned short)r;
}
__device__ __forceinline__ float bf2f(unsigned short h) {
    union { unsigned u; float f; } c; c.u = ((unsigned)h) << 16;
    return c.f;
}
__device__ __forceinline__ float blo(unsigned w) { return bf2f((unsigned short)(w & 0xffffu)); }
__device__ __forceinline__ float bhi(unsigned w) { return bf2f((unsigned short)(w >> 16)); }
__device__ __forceinline__ unsigned bpack(float a, float b) {
    return (unsigned)f2bf(a) | ((unsigned)f2bf(b) << 16);
}
__device__ __forceinline__ void store8(void* p, unsigned lo, unsigned hi) {
    unsigned long long v = (unsigned long long)lo | ((unsigned long long)hi << 32);
    *(unsigned long long*)p = v;
}

// ---- fp8 e4m3 helpers (sign-aware) ----
__device__ __forceinline__ unsigned char enc_fp8_1(float v) {
#ifdef HAVE_FP8
    return (unsigned char)__builtin_amdgcn_cvt_pk_fp8_f32(v, 0.f, 0, false);
#else
    unsigned sgn = v < 0.f ? 0x80u : 0u;
    float m = fabsf(v);
    unsigned char mag;
    if (m < 0.015625f) {
        int q = (int)(m * 512.0f + 0.5f);
        mag = (unsigned char)(q > 7 ? 7 : q);
    } else {
        union { float f; unsigned u; } c; c.f = m;
        unsigned r = c.u + 0x7ffff + ((c.u >> 20) & 1u);
        int e = (int)(r >> 23) - 127;
        mag = (e > 8) ? (unsigned char)0x7e : (unsigned char)(((e + 7) << 3) | ((r >> 20) & 7u));
    }
    return (unsigned char)(sgn | mag);
#endif
}
__device__ __forceinline__ unsigned enc_fp8x4(float v0, float v1, float v2, float v3) {
#ifdef HAVE_FP8
    int r = __builtin_amdgcn_cvt_pk_fp8_f32(v0, v1, 0, false);
    r = __builtin_amdgcn_cvt_pk_fp8_f32(v2, v3, r, true);
    return (unsigned)r;
#else
    return (unsigned)enc_fp8_1(v0) | ((unsigned)enc_fp8_1(v1) << 8) |
           ((unsigned)enc_fp8_1(v2) << 16) | ((unsigned)enc_fp8_1(v3) << 24);
#endif
}
__device__ __forceinline__ void dec_fp8x4(unsigned w, float& x0, float& x1, float& x2, float& x3) {
#ifdef HAVE_FP8
    f32x2 lo = __builtin_amdgcn_cvt_pk_f32_fp8((int)w, false);
    f32x2 hi = __builtin_amdgcn_cvt_pk_f32_fp8((int)w, true);
    x0 = lo.x; x1 = lo.y; x2 = hi.x; x3 = hi.y;
#else
    auto d1 = [](unsigned b) -> float {
        float s = (b & 0x80u) ? -1.f : 1.f;
        b &= 0x7fu;
        if (b < 8) return s * (float)b * 0.001953125f;
        union { unsigned u; float f; } c;
        c.u = ((((b >> 3) & 15u) - 7 + 127) << 23) | ((b & 7u) << 20);
        return s * c.f;
    };
    x0 = d1(w & 0xffu); x1 = d1((w >> 8) & 0xffu);
    x2 = d1((w >> 16) & 0xffu); x3 = d1(w >> 24);
#endif
}
// decode 8 fp8 bytes -> short8 of bf16 (exact: fp8 values are bf16-representable)
__device__ __forceinline__ short8 dec8bf(uint2 v) {
    float x0, x1, x2, x3, y0, y1, y2, y3;
    dec_fp8x4(v.x, x0, x1, x2, x3);
    dec_fp8x4(v.y, y0, y1, y2, y3);
    union { short8 s; unsigned u[4]; } r;
    r.u[0] = bpack(x0, x1); r.u[1] = bpack(x2, x3);
    r.u[2] = bpack(y0, y1); r.u[3] = bpack(y2, y3);
    return r.s;
}

// ---------------- binned CSR fill (fixed-capacity buckets) ----------------

__global__ __launch_bounds__(256) void k_bin(const int* __restrict__ src,
                                             const int* __restrict__ dst,
                                             int* __restrict__ bucket_fill,
                                             unsigned* __restrict__ bbuf) {
    __shared__ int cnt[NB];
    __shared__ int base[NB];
    int t = threadIdx.x;
    for (int i = t; i < NB; i += 256) cnt[i] = 0;
    __syncthreads();
    int e0 = blockIdx.x * BIN_EPB;
    int e1 = e0 + BIN_EPB < N_EDGES ? e0 + BIN_EPB : N_EDGES;
    for (int e = e0 + t; e < e1; e += 256) {
        atomicAdd(&cnt[dst[e] >> 8], 1);
    }
    __syncthreads();
    for (int i = t; i < NB; i += 256) {
        int c = cnt[i];
        base[i] = c ? atomicAdd(&bucket_fill[i], c) : 0;
        cnt[i] = 0;
    }
    __syncthreads();
    for (int e = e0 + t; e < e1; e += 256) {
        int d = dst[e];
        int b = d >> 8;
        int pos = atomicAdd(&cnt[b], 1);
        bbuf[(size_t)b * BKCAP + base[b] + pos] = ((unsigned)src[e] << 8) | (unsigned)(d & 255);
    }
}

__global__ __launch_bounds__(256) void k_scatter(const unsigned* __restrict__ bbuf,
                                                 const int* __restrict__ bucket_fill,
                                                 int2* __restrict__ rp2,
                                                 int* __restrict__ csr) {
    __shared__ int fc[256];
    __shared__ int ofs[256];
    __shared__ int wsum[4];
    int b = blockIdx.x, t = threadIdx.x;
    int nstart = b << 8;
    int base = b * BKCAP;
    int bend = base + bucket_fill[b];
    fc[t] = 0;
    __syncthreads();
    for (int i = base + t; i < bend; i += 256)
        atomicAdd(&fc[bbuf[i] & 255u], 1);
    __syncthreads();
    int d = fc[t];
    int dp = (d + 7) & ~7;               // padded degree (multiple of 8)
    int lane = t & 63, w = t >> 6;
    int inc = dp;
    #pragma unroll
    for (int o = 1; o < 64; o <<= 1) {
        int x = __shfl_up(inc, o, 64);
        if (lane >= o) inc += x;
    }
    if (lane == 63) wsum[w] = inc;
    __syncthreads();
    int woff = 0;
    for (int i = 0; i < w; ++i) woff += wsum[i];
    ofs[t] = base + woff + inc - dp;
    __syncthreads();
    int node = nstart + t;
    int o0 = ofs[t];
    if (node < N_NODES) rp2[node] = make_int2(o0, o0 + d);
    for (int i = o0 + d; i < o0 + dp; ++i) csr[i] = ZROW;
    fc[t] = 0;
    __syncthreads();
    for (int i = base + t; i < bend; i += 256) {
        unsigned p = bbuf[i];
        int dl = (int)(p & 255u);
        int pos = atomicAdd(&fc[dl], 1);
        csr[ofs[dl] + pos] = (int)(p >> 8);
    }
}

// ---------------- feats -> bf16 copy [N][80] + fp8 copy [N][80B]; zero rows at ZROW ----------------

__global__ void k_feats(const float* __restrict__ feats, short* __restrict__ fbf,
                        unsigned* __restrict__ f8t, unsigned* __restrict__ h1c8) {
    int idx = blockIdx.x * blockDim.x + threadIdx.x;  // 4-col group index
    if (idx < H1C8_LD / 4) h1c8[(size_t)ZROW * (H1C8_LD / 4) + idx] = 0u;  // h1c8 zero row
    if (idx >= (N_NODES + 1) * (F8T_LD / 4)) return;
    int n = idx / (F8T_LD / 4), g = idx - n * (F8T_LD / 4);
    int c0 = 4 * g;
    float v0 = 0.f, v1 = 0.f, v2 = 0.f, v3 = 0.f;
    if (n < N_NODES) {
        const float* r = feats + (size_t)n * F_IN;
        v0 = (c0 + 0 < F_IN) ? r[c0 + 0] : 0.f;
        v1 = (c0 + 1 < F_IN) ? r[c0 + 1] : 0.f;
        v2 = (c0 + 2 < F_IN) ? r[c0 + 2] : 0.f;
        v3 = (c0 + 3 < F_IN) ? r[c0 + 3] : 0.f;
    }
    unsigned* fb = (unsigned*)fbf + (size_t)n * (FBF_LD / 2) + 2 * g;
    fb[0] = bpack(v0, v1);
    fb[1] = bpack(v2, v3);
    f8t[idx] = enc_fp8x4(v0, v1, v2, v3);
}

// ---------------- Weight preconvert: Wt[col][k], bf16 hi/lo ----------------

template <int KP, int K1, int AGG0>
__global__ void k_wconv(const float* __restrict__ Ws, const float* __restrict__ Wn,
                        short* __restrict__ Whi, short* __restrict__ Wlo) {
    int idx = blockIdx.x * blockDim.x + threadIdx.x;
    if (idx >= 112 * KP) return;
    int col = idx / KP, k = idx - col * KP;
    float v = 0.f;
    if (col < HID) {
        if (k < K1) v = Ws[k * HID + col];
        else if (k >= AGG0 && k < AGG0 + K1) v = Wn[(k - AGG0) * HID + col];
    }
    unsigned short hi = f2bf(v);
    unsigned short lo = f2bf(v - bf2f(hi));
    Whi[idx] = (short)hi;
    Wlo[idx] = (short)lo;
}

// ---------------- prep1: agt[v] = mean-agg of fp8 neighbor feats (bf16 out, 80 cols) ----------------

__global__ __launch_bounds__(256) void k_prep1(const unsigned char* __restrict__ f8t,
                        const int2* __restrict__ rp2, const int* __restrict__ csr,
                        short* __restrict__ agt) {
    int wid = threadIdx.x >> 6, lane = threadIdx.x & 63;
    int v = blockIdx.x * 4 + wid;
    if (v >= N_NODES) return;
    int h = lane >> 5, q = lane & 31;
    int2 se = rp2[v];
    int s = se.x, e = se.y;
    int deg = e - s;
    int pe = s + ((deg + 7) & ~7);
    float a0 = 0.f, a1 = 0.f, a2 = 0.f, a3 = 0.f;
    if (q < 19) {
        #pragma unroll 2
        for (int j = s; j < pe; j += 8) {
            unsigned w0 = *(const unsigned*)(f8t + (size_t)csr[j + h] * F8T_LD + q * 4);
            unsigned w1 = *(const unsigned*)(f8t + (size_t)csr[j + 2 + h] * F8T_LD + q * 4);
            unsigned w2 = *(const unsigned*)(f8t + (size_t)csr[j + 4 + h] * F8T_LD + q * 4);
            unsigned w3 = *(const unsigned*)(f8t + (size_t)csr[j + 6 + h] * F8T_LD + q * 4);
            float x0, x1, x2, x3;
            dec_fp8x4(w0, x0, x1, x2, x3); a0 += x0; a1 += x1; a2 += x2; a3 += x3;
            dec_fp8x4(w1, x0, x1, x2, x3); a0 += x0; a1 += x1; a2 += x2; a3 += x3;
            dec_fp8x4(w2, x0, x1, x2, x3); a0 += x0; a1 += x1; a2 += x2; a3 += x3;
            dec_fp8x4(w3, x0, x1, x2, x3); a0 += x0; a1 += x1; a2 += x2; a3 += x3;
        }
    }
    a0 += __shfl_xor(a0, 32, 64);
    a1 += __shfl_xor(a1, 32, 64);
    a2 += __shfl_xor(a2, 32, 64);
    a3 += __shfl_xor(a3, 32, 64);
    float inv = 1.0f / fmaxf((float)deg, 1.0f);
    if (h == 0 && q < 20) {  // shorts 4q..4q+3 (q=19 -> zeros)
        store8((char*)agt + (size_t)v * (AGT_LD * 2) + q * 8,
               bpack(a0 * inv, a1 * inv), bpack(a2 * inv, a3 * inv));
    }
}

// ---------------- prep2: agt2[v] = mean-agg of fp8 h1 (bf16 out, 112 cols, 100..111 zero) ----------------

__global__ __launch_bounds__(256) void k_prep2(const unsigned char* __restrict__ h1c8,
                        const int2* __restrict__ rp2, const int* __restrict__ csr,
                        short* __restrict__ agt2) {
    int wid = threadIdx.x >> 6, lane = threadIdx.x & 63;
    int v = blockIdx.x * 4 + wid;
    if (v >= N_NODES) return;
    int h = lane >> 5, q = lane & 31;
    int2 se = rp2[v];
    int s = se.x, e = se.y;
    int deg = e - s;
    int pe = s + ((deg + 7) & ~7);
    float a0 = 0.f, a1 = 0.f, a2 = 0.f, a3 = 0.f;
    if (q < 25) {
        #pragma unroll 2
        for (int j = s; j < pe; j += 8) {
            unsigned w0 = *(const unsigned*)(h1c8 + (size_t)csr[j + h] * H1C8_LD + q * 4);
            unsigned w1 = *(const unsigned*)(h1c8 + (size_t)csr[j + 2 + h] * H1C8_LD + q * 4);
            unsigned w2 = *(const unsigned*)(h1c8 + (size_t)csr[j + 4 + h] * H1C8_LD + q * 4);
            unsigned w3 = *(const unsigned*)(h1c8 + (size_t)csr[j + 6 + h] * H1C8_LD + q * 4);
            float x0, x1, x2, x3;
            dec_fp8x4(w0, x0, x1, x2, x3); a0 += x0; a1 += x1; a2 += x2; a3 += x3;
            dec_fp8x4(w1, x0, x1, x2, x3); a0 += x0; a1 += x1; a2 += x2; a3 += x3;
            dec_fp8x4(w2, x0, x1, x2, x3); a0 += x0; a1 += x1; a2 += x2; a3 += x3;
            dec_fp8x4(w3, x0, x1, x2, x3); a0 += x0; a1 += x1; a2 += x2; a3 += x3;
        }
    }
    a0 += __shfl_xor(a0, 32, 64);
    a1 += __shfl_xor(a1, 32, 64);
    a2 += __shfl_xor(a2, 32, 64);
    a3 += __shfl_xor(a3, 32, 64);
    float inv = 1.0f / fmaxf((float)deg, 1.0f);
    char* Aw = (char*)agt2 + (size_t)v * (AGT2_LD * 2);      // 224B row
    if (h == 0 && q < 25) {                                   // agg: shorts 4q..4q+3
        store8(Aw + q * 8, bpack(a0 * inv, a1 * inv), bpack(a2 * inv, a3 * inv));
    }
    if (h == 1 && q < 3) {                                    // zeros: shorts 100..111
        store8(Aw + 200 + q * 8, 0u, 0u);
    }
}

// ---------------- mfma1: h1 = relu([fbf|agt] @ Wt1^T + b1) -> h1c8 (fp8) ----------------
// 2-way n-split: nh=0 cols 0..63, nh=1 cols 64..111. 2 waves/block, 32 rows/wave; A prefetched.

__global__ __launch_bounds__(128) void k_mfma1(
    const short* __restrict__ fbf, const short* __restrict__ agt,
    const short* __restrict__ Wthi, const short* __restrict__ Wtlo,
    const float* __restrict__ bias, unsigned char* __restrict__ h1c8) {
    int t = threadIdx.x;
    int nh = blockIdx.x & 1, rb = blockIdx.x >> 1;
    const int NG = nh ? 3 : 4;
    const int ng0 = nh ? 4 : 0;
    int wid = t >> 6, lane = t & 63;
    int quad = lane >> 4, lr = lane & 15;
    int rowbase = rb * 64 + wid * 32;

    short8 ap[2][5];
    #pragma unroll
    for (int rf = 0; rf < 2; ++rf) {
        int row = rowbase + rf * 16 + lr;
        #pragma unroll
        for (int c = 0; c < 5; ++c) {
            const short* p;
            if (c < 2) p = fbf + (size_t)row * FBF_LD + c * 32 + quad * 8;
            else if (c == 2) p = (quad < 2) ? fbf + (size_t)row * FBF_LD + 64 + quad * 8
                                            : agt + (size_t)row * AGT_LD + (quad - 2) * 8;
            else p = agt + (size_t)row * AGT_LD + (c - 3) * 32 + 16 + quad * 8;
            ap[rf][c] = *(const short8*)p;
        }
    }

    f32x4 acc[2][4];
    #pragma unroll
    for (int rf = 0; rf < 2; ++rf)
        #pragma unroll
        for (int n = 0; n < 4; ++n) acc[rf][n] = (f32x4){0.f, 0.f, 0.f, 0.f};

    #pragma unroll
    for (int c = 0; c < 5; ++c) {
        #pragma unroll
        for (int n = 0; n < 4; ++n) {
            if (n < NG) {
                size_t off = (size_t)((ng0 + n) * 16 + lr) * KP1 + c * 32 + quad * 8;
                short8 wh = *(const short8*)(Wthi + off);
                short8 wl = *(const short8*)(Wtlo + off);
                #pragma unroll
                for (int rf = 0; rf < 2; ++rf) {
                    acc[rf][n] = __builtin_amdgcn_mfma_f32_16x16x32_bf16(ap[rf][c], wh, acc[rf][n], 0, 0, 0);
                    acc[rf][n] = __builtin_amdgcn_mfma_f32_16x16x32_bf16(ap[rf][c], wl, acc[rf][n], 0, 0, 0);
                }
            }
        }
    }

    #pragma unroll
    for (int rf = 0; rf < 2; ++rf) {
        #pragma unroll
        for (int n = 0; n < 4; ++n) {
            if (n < NG) {
                int col = (ng0 + n) * 16 + lr;             // 0..111
                float bv = (col < HID) ? bias[col] : 0.f;
                #pragma unroll
                for (int r = 0; r < 4; ++r) {
                    int row = rowbase + rf * 16 + quad * 4 + r;
                    if (row < N_NODES) {
                        unsigned char enc = 0;
                        if (col < HID) enc = enc_fp8_1(fmaxf(acc[rf][n][r] + bv, 0.f));
                        h1c8[(size_t)row * H1C8_LD + col] = enc;
                    }
                }
            }
        }
        if (nh == 1) {  // zero cols 112..127 (complete 128B rows)
            #pragma unroll
            for (int r = 0; r < 4; ++r) {
                int row = rowbase + rf * 16 + quad * 4 + r;
                if (row < N_NODES) h1c8[(size_t)row * H1C8_LD + 112 + lr] = 0;
            }
        }
    }
}

// ---------------- mfma2: h2 = relu([h1c8|agt2] @ Wt2^T + b2) -> bf16 [N][100] + partial aw ----------------
// 4-way n-split: nh in 0..3, NG={2,2,2,1}, ng0=2*nh. Partial dot in awp[nh*N + row].

__global__ __launch_bounds__(128) void k_mfma2(
    const unsigned char* __restrict__ h1c8, const short* __restrict__ agt2,
    const short* __restrict__ Wthi, const short* __restrict__ Wtlo,
    const float* __restrict__ bias, const float* __restrict__ w_atom,
    short* __restrict__ h2c, float* __restrict__ awp) {
    int t = threadIdx.x;
    int nh = blockIdx.x & 3, rb = blockIdx.x >> 2;
    const int NG = (nh < 3) ? 2 : 1;
    const int ng0 = nh * 2;
    int wid = t >> 6, lane = t & 63;
    int quad = lane >> 4, lr = lane & 15;
    int rowbase = rb * 64 + wid * 32;

    short8 ap[2][7];
    #pragma unroll
    for (int rf = 0; rf < 2; ++rf) {
        int row = rowbase + rf * 16 + lr;
        const unsigned char* hr = h1c8 + (size_t)row * H1C8_LD;
        const short* ar = agt2 + (size_t)row * AGT2_LD;
        #pragma unroll
        for (int c = 0; c < 7; ++c) {
            if (c < 3) {
                ap[rf][c] = dec8bf(*(const uint2*)(hr + c * 32 + quad * 8));
            } else if (c == 3) {
                if (quad < 2) ap[rf][c] = dec8bf(*(const uint2*)(hr + 96 + quad * 8));
                else ap[rf][c] = *(const short8*)(ar + (quad - 2) * 8);
            } else {
                ap[rf][c] = *(const short8*)(ar + (c - 4) * 32 + 16 + quad * 8);
            }
        }
    }

    f32x4 acc[2][2];
    #pragma unroll
    for (int rf = 0; rf < 2; ++rf)
        #pragma unroll
        for (int n = 0; n < 2; ++n) acc[rf][n] = (f32x4){0.f, 0.f, 0.f, 0.f};

    #pragma unroll
    for (int c = 0; c < 7; ++c) {
        #pragma unroll
        for (int n = 0; n < 2; ++n) {
            if (n < NG) {
                size_t off = (size_t)((ng0 + n) * 16 + lr) * KP2 + c * 32 + quad * 8;
                short8 wh = *(const short8*)(Wthi + off);
                short8 wl = *(const short8*)(Wtlo + off);
                #pragma unroll
                for (int rf = 0; rf < 2; ++rf) {
                    acc[rf][n] = __builtin_amdgcn_mfma_f32_16x16x32_bf16(ap[rf][c], wh, acc[rf][n], 0, 0, 0);
                    acc[rf][n] = __builtin_amdgcn_mfma_f32_16x16x32_bf16(ap[rf][c], wl, acc[rf][n], 0, 0, 0);
                }
            }
        }
    }

    #pragma unroll
    for (int rf = 0; rf < 2; ++rf) {
        float dotr0 = 0.f, dotr1 = 0.f, dotr2 = 0.f, dotr3 = 0.f;
        #pragma unroll
        for (int n = 0; n < 2; ++n) {
            if (n < NG) {
                int col = (ng0 + n) * 16 + lr;
                if (col < HID) {
                    float bv = bias[col];
                    float wa = w_atom[col];
                    #pragma unroll
                    for (int r = 0; r < 4; ++r) {
                        int row = rowbase + rf * 16 + quad * 4 + r;
                        if (row < N_NODES) {
                            float v = fmaxf(acc[rf][n][r] + bv, 0.f);
                            h2c[(size_t)row * H2_LD + col] = (short)f2bf(v);
                            float dv = v * wa;
                            if (r == 0) dotr0 += dv;
                            else if (r == 1) dotr1 += dv;
                            else if (r == 2) dotr2 += dv;
                            else dotr3 += dv;
                        }
                    }
                }
            }
        }
        #pragma unroll
        for (int off = 1; off < 16; off <<= 1) {
            dotr0 += __shfl_xor(dotr0, off, 64);
            dotr1 += __shfl_xor(dotr1, off, 64);
            dotr2 += __shfl_xor(dotr2, off, 64);
            dotr3 += __shfl_xor(dotr3, off, 64);
        }
        if (lr == 0) {
            int row0 = rowbase + rf * 16 + quad * 4;
            float d[4] = {dotr0, dotr1, dotr2, dotr3};
            #pragma unroll
            for (int r = 0; r < 4; ++r) {
                int row = row0 + r;
                if (row < N_NODES) awp[(size_t)nh * N_NODES + row] = d[r];
            }
        }
    }
}

// ---------------- Collapsed predictor head: w_eff[200], b_eff ----------------

__global__ void k_weff(const float* __restrict__ Wp1, const float* __restrict__ bp1,
                       const float* __restrict__ Wp2, const float* __restrict__ bp2,
                       float* __restrict__ weff) {
    int t = threadIdx.x;
    if (t < 200) {
        float s = 0.f;
        for (int k = 0; k < 64; ++k) s += Wp1[t * 64 + k] * Wp2[k];
        weff[t] = s;
    } else if (t == 200) {
        float s = bp2[0];
        for (int k = 0; k < 64; ++k) s += bp1[k] * Wp2[k];
        weff[200] = s;
    }
}

// ---------------- Readout: per-graph weighted sum + max (aw from 4 partials), fused head ----------------

__global__ __launch_bounds__(256) void k_readout(
    const unsigned short* __restrict__ h2c, const float* __restrict__ awp,
    const int* __restrict__ graph_ids, const float* __restrict__ weff,
    const float* __restrict__ b_atom, float* __restrict__ out) {
    int g = blockIdx.x;
    int t = threadIdx.x, lane = t & 63, w = t >> 6;

    int s_, e_;
    {
        int l = 0, r = N_NODES;
        while (l < r) { int m = (l + r) >> 1; if (graph_ids[m] < g) l = m + 1; else r = m; }
        s_ = l;
        l = s_; r = N_NODES;
        while (l < r) { int m = (l + r) >> 1; if (graph_ids[m] < g + 1) l = m + 1; else r = m; }
        e_ = l;
    }

    float ba = b_atom[0];
    float sum0 = 0.f, sum1 = 0.f, mx0 = 0.f, mx1 = 0.f;  // h >= 0 (relu)
    for (int i = s_ + w; i < e_; i += 4) {
        float dot = (awp[i] + awp[N_NODES + i]) +
                    (awp[2 * N_NODES + i] + awp[3 * N_NODES + i]);
        float wt = 1.f / (1.f + __expf(-(dot + ba)));
        if (lane < 50) {
            unsigned wv = *(const unsigned*)(h2c + (size_t)i * H2_LD + 2 * lane);
            float v0 = blo(wv), v1 = bhi(wv);
            sum0 += v0 * wt;
            sum1 += v1 * wt;
            mx0 = fmaxf(mx0, v0);
            mx1 = fmaxf(mx1, v1);
        }
    }

    __shared__ float ssum[4][HID];
    __shared__ float smx[4][HID];
    if (lane < 50) {
        ssum[w][2 * lane] = sum0;
        ssum[w][2 * lane + 1] = sum1;
        smx[w][2 * lane] = mx0;
        smx[w][2 * lane + 1] = mx1;
    }
    __syncthreads();

    float contrib = 0.f;
    if (t < HID) {
        float sumf = ssum[0][t] + ssum[1][t] + ssum[2][t] + ssum[3][t];
        float mxf = fmaxf(fmaxf(smx[0][t], smx[1][t]), fmaxf(smx[2][t], smx[3][t]));
        contrib = sumf * weff[t] + mxf * weff[HID + t];
    }
    #pragma unroll
    for (int off = 32; off; off >>= 1) contrib += __shfl_xor(contrib, off, 64);
    __shared__ float red[4];
    if (lane == 0) red[w] = contrib;
    __syncthreads();
    if (t == 0) out[g] = red[0] + red[1] + red[2] + red[3] + weff[200];
}

// ---------------- launch ----------------

extern "C" void kernel_launch(void* const* d_in, const int* in_sizes, int n_in,
                              void* d_out, int out_size, void* d_ws, size_t ws_size,
                              hipStream_t stream) {
    const float* node_feats = (const float*)d_in[0];
    const int* src = (const int*)d_in[1];
    const int* dst = (const int*)d_in[2];
    const int* gid = (const int*)d_in[3];
    const float* Ws1 = (const float*)d_in[5];
    const float* Wn1 = (const float*)d_in[6];
    const float* b1 = (const float*)d_in[7];
    const float* Ws2 = (const float*)d_in[8];
    const float* Wn2 = (const float*)d_in[9];
    const float* b2 = (const float*)d_in[10];
    const float* w_atom = (const float*)d_in[11];
    const float* b_atom = (const float*)d_in[12];
    const float* Wp1 = (const float*)d_in[13];
    const float* bp1 = (const float*)d_in[14];
    const float* Wp2 = (const float*)d_in[15];
    const float* bp2 = (const float*)d_in[16];
    float* out = (float*)d_out;

    char* ws = (char*)d_ws;
    size_t off = 0;
    auto alloc = [&](size_t bytes) -> void* {
        void* p = (void*)(ws + off);
        off += (bytes + 255) & ~(size_t)255;
        return p;
    };
    int2* rp2 = (int2*)alloc((size_t)N_NODES * sizeof(int2));
    int* bucket_fill = (int*)alloc(NB * sizeof(int));
    int* csr = (int*)alloc((size_t)NB * BKCAP * sizeof(int));                 // 12.8 MB
    unsigned* bbuf = (unsigned*)alloc((size_t)NB * BKCAP * sizeof(unsigned)); // 12.8 MB
    short* fbf = (short*)alloc((size_t)(N_PAD + 1) * FBF_LD * sizeof(short)); // 16 MB
    unsigned char* f8t = (unsigned char*)alloc((size_t)(N_PAD + 1) * F8T_LD); // 8 MB
    short* agt = (short*)alloc((size_t)N_PAD * AGT_LD * sizeof(short));       // 16 MB
    short* agt2 = (short*)alloc((size_t)N_PAD * AGT2_LD * sizeof(short));     // 22.4 MB
    unsigned char* h1c8 = (unsigned char*)alloc((size_t)(N_NODES + 1) * H1C8_LD); // 12.8 MB
    short* h2c = (short*)alloc((size_t)N_NODES * H2_LD * sizeof(short));      // 20 MB
    float* awp = (float*)alloc((size_t)4 * N_NODES * sizeof(float));          // 1.6 MB
    short* Wt1hi = (short*)alloc(112 * KP1 * sizeof(short));
    short* Wt1lo = (short*)alloc(112 * KP1 * sizeof(short));
    short* Wt2hi = (short*)alloc(112 * KP2 * sizeof(short));
    short* Wt2lo = (short*)alloc(112 * KP2 * sizeof(short));
    float* weff = (float*)alloc(256 * sizeof(float));

    hipMemsetAsync(bucket_fill, 0, NB * sizeof(int), stream);

    k_bin<<<NBB, 256, 0, stream>>>(src, dst, bucket_fill, bbuf);
    k_scatter<<<NB, 256, 0, stream>>>(bbuf, bucket_fill, rp2, csr);

    k_feats<<<((N_NODES + 1) * (F8T_LD / 4) + 255) / 256, 256, 0, stream>>>(
        node_feats, fbf, (unsigned*)f8t, (unsigned*)h1c8);
    k_wconv<KP1, F_IN, 80><<<(112 * KP1 + 255) / 256, 256, 0, stream>>>(Ws1, Wn1, Wt1hi, Wt1lo);
    k_wconv<KP2, HID, 112><<<(112 * KP2 + 255) / 256, 256, 0, stream>>>(Ws2, Wn2, Wt2hi, Wt2lo);

    k_prep1<<<(N_NODES + 3) / 4, 256, 0, stream>>>(f8t, rp2, csr, agt);
    k_mfma1<<<(N_PAD / 64) * 2, 128, 0, stream>>>(fbf, agt, Wt1hi, Wt1lo, b1, h1c8);
    k_prep2<<<(N_NODES + 3) / 4, 256, 0, stream>>>(h1c8, rp2, csr, agt2);
    k_mfma2<<<(N_PAD / 64) * 4, 128, 0, stream>>>(h1c8, agt2, Wt2hi, Wt2lo, b2, w_atom, h2c, awp);

    k_weff<<<1, 256, 0, stream>>>(Wp1, bp1, Wp2, bp2, weff);
    k_readout<<<N_GRAPHS, 256, 0, stream>>>((const unsigned short*)h2c, awp, gid, weff, b_atom, out);
}

// Round 22
// 237.493 us; speedup vs baseline: 1.0544x; 1.0544x over previous
//
#include <hip/hip_runtime.h>

#define N_NODES 100000
#define N_PAD   100096
#define N_EDGES 1600000
#define N_GRAPHS 1024
#define F_IN 74
#define HID 100

#define KP1 160   // W1: [self 0..73 | 0 | agg 80..153 | 0]; A from fbf(k<80)+agt(k>=80)
#define KP2 224   // W2: [self 0..99 | 0 100..111 | agg 112..211 | 0 212..223]

#define FBF_LD 80    // bf16 feats rows (160B)
#define F8T_LD 80    // fp8 feats rows (80B)
#define AGT_LD 80    // bf16 agg1 rows (160B)
#define AGT2_LD 112  // bf16 agg2 rows (224B, cols 100..111 zero)
#define H1C8_LD 128  // fp8 h1 compact rows (128B, cols 100..127 zero)
#define H2_LD  100   // bf16 h2 rows (200B)

#define ZROW N_NODES                 // zero-row index for degree padding

#define NB ((N_NODES + 255) / 256)   // 391 dst-buckets of 256 nodes
#define BKCAP 8192                   // bbuf/csr slots per bucket
#define BIN_EPB 4096                 // edges per binning block
#define NBB ((N_EDGES + BIN_EPB - 1) / BIN_EPB)

typedef __attribute__((ext_vector_type(8))) short short8;
typedef __attribute__((ext_vector_type(4))) float f32x4;
typedef __attribute__((ext_vector_type(2))) float f32x2;

#if defined(__has_builtin)
#if __has_builtin(__builtin_amdgcn_cvt_pk_f32_fp8) && __has_builtin(__builtin_amdgcn_cvt_pk_fp8_f32)
#define HAVE_FP8 1
#endif
#endif

__device__ __forceinline__ unsigned short f2bf(float x) {
    union { float f; unsigned u; } c; c.f = x;
    unsigned u = c.u;
    unsigned r = (u + 0x7fffu + ((u >> 16) & 1u)) >> 16;
    return (unsigned short)r;
}
__device__ __forceinline__ float bf2f(unsigned short h) {
    union { unsigned u; float f; } c; c.u = ((unsigned)h) << 16;
    return c.f;
}
__device__ __forceinline__ float blo(unsigned w) { return bf2f((unsigned short)(w & 0xffffu)); }
__device__ __forceinline__ float bhi(unsigned w) { return bf2f((unsigned short)(w >> 16)); }
__device__ __forceinline__ unsigned bpack(float a, float b) {
    return (unsigned)f2bf(a) | ((unsigned)f2bf(b) << 16);
}
__device__ __forceinline__ void store8(void* p, unsigned lo, unsigned hi) {
    unsigned long long v = (unsigned long long)lo | ((unsigned long long)hi << 32);
    *(unsigned long long*)p = v;
}

// ---- fp8 e4m3 helpers (sign-aware) ----
__device__ __forceinline__ unsigned char enc_fp8_1(float v) {
#ifdef HAVE_FP8
    return (unsigned char)__builtin_amdgcn_cvt_pk_fp8_f32(v, 0.f, 0, false);
#else
    unsigned sgn = v < 0.f ? 0x80u : 0u;
    float m = fabsf(v);
    unsigned char mag;
    if (m < 0.015625f) {
        int q = (int)(m * 512.0f + 0.5f);
        mag = (unsigned char)(q > 7 ? 7 : q);
    } else {
        union { float f; unsigned u; } c; c.f = m;
        unsigned r = c.u + 0x7ffff + ((c.u >> 20) & 1u);
        int e = (int)(r >> 23) - 127;
        mag = (e > 8) ? (unsigned char)0x7e : (unsigned char)(((e + 7) << 3) | ((r >> 20) & 7u));
    }
    return (unsigned char)(sgn | mag);
#endif
}
__device__ __forceinline__ unsigned enc_fp8x4(float v0, float v1, float v2, float v3) {
#ifdef HAVE_FP8
    int r = __builtin_amdgcn_cvt_pk_fp8_f32(v0, v1, 0, false);
    r = __builtin_amdgcn_cvt_pk_fp8_f32(v2, v3, r, true);
    return (unsigned)r;
#else
    return (unsigned)enc_fp8_1(v0) | ((unsigned)enc_fp8_1(v1) << 8) |
           ((unsigned)enc_fp8_1(v2) << 16) | ((unsigned)enc_fp8_1(v3) << 24);
#endif
}
__device__ __forceinline__ void dec_fp8x4(unsigned w, float& x0, float& x1, float& x2, float& x3) {
#ifdef HAVE_FP8
    f32x2 lo = __builtin_amdgcn_cvt_pk_f32_fp8((int)w, false);
    f32x2 hi = __builtin_amdgcn_cvt_pk_f32_fp8((int)w, true);
    x0 = lo.x; x1 = lo.y; x2 = hi.x; x3 = hi.y;
#else
    auto d1 = [](unsigned b) -> float {
        float s = (b & 0x80u) ? -1.f : 1.f;
        b &= 0x7fu;
        if (b < 8) return s * (float)b * 0.001953125f;
        union { unsigned u; float f; } c;
        c.u = ((((b >> 3) & 15u) - 7 + 127) << 23) | ((b & 7u) << 20);
        return s * c.f;
    };
    x0 = d1(w & 0xffu); x1 = d1((w >> 8) & 0xffu);
    x2 = d1((w >> 16) & 0xffu); x3 = d1(w >> 24);
#endif
}
// decode 8 fp8 bytes -> short8 of bf16 (exact: fp8 values are bf16-representable)
__device__ __forceinline__ short8 dec8bf(uint2 v) {
    float x0, x1, x2, x3, y0, y1, y2, y3;
    dec_fp8x4(v.x, x0, x1, x2, x3);
    dec_fp8x4(v.y, y0, y1, y2, y3);
    union { short8 s; unsigned u[4]; } r;
    r.u[0] = bpack(x0, x1); r.u[1] = bpack(x2, x3);
    r.u[2] = bpack(y0, y1); r.u[3] = bpack(y2, y3);
    return r.s;
}

// ---------------- binned CSR fill (fixed-capacity buckets) ----------------

__global__ __launch_bounds__(256) void k_bin(const int* __restrict__ src,
                                             const int* __restrict__ dst,
                                             int* __restrict__ bucket_fill,
                                             unsigned* __restrict__ bbuf) {
    __shared__ int cnt[NB];
    __shared__ int base[NB];
    int t = threadIdx.x;
    for (int i = t; i < NB; i += 256) cnt[i] = 0;
    __syncthreads();
    int e0 = blockIdx.x * BIN_EPB;
    int e1 = e0 + BIN_EPB < N_EDGES ? e0 + BIN_EPB : N_EDGES;
    for (int e = e0 + t; e < e1; e += 256) {
        atomicAdd(&cnt[dst[e] >> 8], 1);
    }
    __syncthreads();
    for (int i = t; i < NB; i += 256) {
        int c = cnt[i];
        base[i] = c ? atomicAdd(&bucket_fill[i], c) : 0;
        cnt[i] = 0;
    }
    __syncthreads();
    for (int e = e0 + t; e < e1; e += 256) {
        int d = dst[e];
        int b = d >> 8;
        int pos = atomicAdd(&cnt[b], 1);
        bbuf[(size_t)b * BKCAP + base[b] + pos] = ((unsigned)src[e] << 8) | (unsigned)(d & 255);
    }
}

__global__ __launch_bounds__(256) void k_scatter(const unsigned* __restrict__ bbuf,
                                                 const int* __restrict__ bucket_fill,
                                                 int2* __restrict__ rp2,
                                                 int* __restrict__ csr) {
    __shared__ int fc[256];
    __shared__ int ofs[256];
    __shared__ int wsum[4];
    int b = blockIdx.x, t = threadIdx.x;
    int nstart = b << 8;
    int base = b * BKCAP;
    int bend = base + bucket_fill[b];
    fc[t] = 0;
    __syncthreads();
    for (int i = base + t; i < bend; i += 256)
        atomicAdd(&fc[bbuf[i] & 255u], 1);
    __syncthreads();
    int d = fc[t];
    int dp = (d + 7) & ~7;               // padded degree (multiple of 8)
    int lane = t & 63, w = t >> 6;
    int inc = dp;
    #pragma unroll
    for (int o = 1; o < 64; o <<= 1) {
        int x = __shfl_up(inc, o, 64);
        if (lane >= o) inc += x;
    }
    if (lane == 63) wsum[w] = inc;
    __syncthreads();
    int woff = 0;
    for (int i = 0; i < w; ++i) woff += wsum[i];
    ofs[t] = base + woff + inc - dp;
    __syncthreads();
    int node = nstart + t;
    int o0 = ofs[t];
    if (node < N_NODES) rp2[node] = make_int2(o0, o0 + d);
    for (int i = o0 + d; i < o0 + dp; ++i) csr[i] = ZROW;
    fc[t] = 0;
    __syncthreads();
    for (int i = base + t; i < bend; i += 256) {
        unsigned p = bbuf[i];
        int dl = (int)(p & 255u);
        int pos = atomicAdd(&fc[dl], 1);
        csr[ofs[dl] + pos] = (int)(p >> 8);
    }
}

// ---------------- feats -> bf16 copy [N][80] + fp8 copy [N][80B]; zero rows at ZROW ----------------

__global__ void k_feats(const float* __restrict__ feats, short* __restrict__ fbf,
                        unsigned* __restrict__ f8t, unsigned* __restrict__ h1c8) {
    int idx = blockIdx.x * blockDim.x + threadIdx.x;  // 4-col group index
    if (idx < H1C8_LD / 4) h1c8[(size_t)ZROW * (H1C8_LD / 4) + idx] = 0u;  // h1c8 zero row
    if (idx >= (N_NODES + 1) * (F8T_LD / 4)) return;
    int n = idx / (F8T_LD / 4), g = idx - n * (F8T_LD / 4);
    int c0 = 4 * g;
    float v0 = 0.f, v1 = 0.f, v2 = 0.f, v3 = 0.f;
    if (n < N_NODES) {
        const float* r = feats + (size_t)n * F_IN;
        v0 = (c0 + 0 < F_IN) ? r[c0 + 0] : 0.f;
        v1 = (c0 + 1 < F_IN) ? r[c0 + 1] : 0.f;
        v2 = (c0 + 2 < F_IN) ? r[c0 + 2] : 0.f;
        v3 = (c0 + 3 < F_IN) ? r[c0 + 3] : 0.f;
    }
    unsigned* fb = (unsigned*)fbf + (size_t)n * (FBF_LD / 2) + 2 * g;
    fb[0] = bpack(v0, v1);
    fb[1] = bpack(v2, v3);
    f8t[idx] = enc_fp8x4(v0, v1, v2, v3);
}

// ---------------- Weight preconvert: Wt[col][k], bf16 hi/lo ----------------

template <int KP, int K1, int AGG0>
__global__ void k_wconv(const float* __restrict__ Ws, const float* __restrict__ Wn,
                        short* __restrict__ Whi, short* __restrict__ Wlo) {
    int idx = blockIdx.x * blockDim.x + threadIdx.x;
    if (idx >= 112 * KP) return;
    int col = idx / KP, k = idx - col * KP;
    float v = 0.f;
    if (col < HID) {
        if (k < K1) v = Ws[k * HID + col];
        else if (k >= AGG0 && k < AGG0 + K1) v = Wn[(k - AGG0) * HID + col];
    }
    unsigned short hi = f2bf(v);
    unsigned short lo = f2bf(v - bf2f(hi));
    Whi[idx] = (short)hi;
    Wlo[idx] = (short)lo;
}

// ---------------- prep1: agt[v] = mean-agg of fp8 neighbor feats (bf16 out, 80 cols) ----------------

__global__ __launch_bounds__(256) void k_prep1(const unsigned char* __restrict__ f8t,
                        const int2* __restrict__ rp2, const int* __restrict__ csr,
                        short* __restrict__ agt) {
    int wid = threadIdx.x >> 6, lane = threadIdx.x & 63;
    int v = blockIdx.x * 4 + wid;
    if (v >= N_NODES) return;
    int h = lane >> 5, q = lane & 31;
    int2 se = rp2[v];
    int s = se.x, e = se.y;
    int deg = e - s;
    int pe = s + ((deg + 7) & ~7);
    float a0 = 0.f, a1 = 0.f, a2 = 0.f, a3 = 0.f;
    if (q < 19) {
        #pragma unroll 2
        for (int j = s; j < pe; j += 8) {
            unsigned w0 = *(const unsigned*)(f8t + (size_t)csr[j + h] * F8T_LD + q * 4);
            unsigned w1 = *(const unsigned*)(f8t + (size_t)csr[j + 2 + h] * F8T_LD + q * 4);
            unsigned w2 = *(const unsigned*)(f8t + (size_t)csr[j + 4 + h] * F8T_LD + q * 4);
            unsigned w3 = *(const unsigned*)(f8t + (size_t)csr[j + 6 + h] * F8T_LD + q * 4);
            float x0, x1, x2, x3;
            dec_fp8x4(w0, x0, x1, x2, x3); a0 += x0; a1 += x1; a2 += x2; a3 += x3;
            dec_fp8x4(w1, x0, x1, x2, x3); a0 += x0; a1 += x1; a2 += x2; a3 += x3;
            dec_fp8x4(w2, x0, x1, x2, x3); a0 += x0; a1 += x1; a2 += x2; a3 += x3;
            dec_fp8x4(w3, x0, x1, x2, x3); a0 += x0; a1 += x1; a2 += x2; a3 += x3;
        }
    }
    a0 += __shfl_xor(a0, 32, 64);
    a1 += __shfl_xor(a1, 32, 64);
    a2 += __shfl_xor(a2, 32, 64);
    a3 += __shfl_xor(a3, 32, 64);
    float inv = 1.0f / fmaxf((float)deg, 1.0f);
    if (h == 0 && q < 20) {  // shorts 4q..4q+3 (q=19 -> zeros)
        store8((char*)agt + (size_t)v * (AGT_LD * 2) + q * 8,
               bpack(a0 * inv, a1 * inv), bpack(a2 * inv, a3 * inv));
    }
}

// ---------------- prep2: agt2[v] = mean-agg of fp8 h1 (bf16 out, 112 cols, 100..111 zero) ----------------

__global__ __launch_bounds__(256) void k_prep2(const unsigned char* __restrict__ h1c8,
                        const int2* __restrict__ rp2, const int* __restrict__ csr,
                        short* __restrict__ agt2) {
    int wid = threadIdx.x >> 6, lane = threadIdx.x & 63;
    int v = blockIdx.x * 4 + wid;
    if (v >= N_NODES) return;
    int h = lane >> 5, q = lane & 31;
    int2 se = rp2[v];
    int s = se.x, e = se.y;
    int deg = e - s;
    int pe = s + ((deg + 7) & ~7);
    float a0 = 0.f, a1 = 0.f, a2 = 0.f, a3 = 0.f;
    if (q < 25) {
        #pragma unroll 2
        for (int j = s; j < pe; j += 8) {
            unsigned w0 = *(const unsigned*)(h1c8 + (size_t)csr[j + h] * H1C8_LD + q * 4);
            unsigned w1 = *(const unsigned*)(h1c8 + (size_t)csr[j + 2 + h] * H1C8_LD + q * 4);
            unsigned w2 = *(const unsigned*)(h1c8 + (size_t)csr[j + 4 + h] * H1C8_LD + q * 4);
            unsigned w3 = *(const unsigned*)(h1c8 + (size_t)csr[j + 6 + h] * H1C8_LD + q * 4);
            float x0, x1, x2, x3;
            dec_fp8x4(w0, x0, x1, x2, x3); a0 += x0; a1 += x1; a2 += x2; a3 += x3;
            dec_fp8x4(w1, x0, x1, x2, x3); a0 += x0; a1 += x1; a2 += x2; a3 += x3;
            dec_fp8x4(w2, x0, x1, x2, x3); a0 += x0; a1 += x1; a2 += x2; a3 += x3;
            dec_fp8x4(w3, x0, x1, x2, x3); a0 += x0; a1 += x1; a2 += x2; a3 += x3;
        }
    }
    a0 += __shfl_xor(a0, 32, 64);
    a1 += __shfl_xor(a1, 32, 64);
    a2 += __shfl_xor(a2, 32, 64);
    a3 += __shfl_xor(a3, 32, 64);
    float inv = 1.0f / fmaxf((float)deg, 1.0f);
    char* Aw = (char*)agt2 + (size_t)v * (AGT2_LD * 2);      // 224B row
    if (h == 0 && q < 25) {                                   // agg: shorts 4q..4q+3
        store8(Aw + q * 8, bpack(a0 * inv, a1 * inv), bpack(a2 * inv, a3 * inv));
    }
    if (h == 1 && q < 3) {                                    // zeros: shorts 100..111
        store8(Aw + 200 + q * 8, 0u, 0u);
    }
}

// ---------------- mfma1: h1 = relu([fbf|agt] @ Wt1^T + b1) -> h1c8 (fp8) ----------------
// 2-way n-split: nh=0 cols 0..63, nh=1 cols 64..111. 2 waves/block, 32 rows/wave; A prefetched.

__global__ __launch_bounds__(128) void k_mfma1(
    const short* __restrict__ fbf, const short* __restrict__ agt,
    const short* __restrict__ Wthi, const short* __restrict__ Wtlo,
    const float* __restrict__ bias, unsigned char* __restrict__ h1c8) {
    int t = threadIdx.x;
    int nh = blockIdx.x & 1, rb = blockIdx.x >> 1;
    const int NG = nh ? 3 : 4;
    const int ng0 = nh ? 4 : 0;
    int wid = t >> 6, lane = t & 63;
    int quad = lane >> 4, lr = lane & 15;
    int rowbase = rb * 64 + wid * 32;

    short8 ap[2][5];
    #pragma unroll
    for (int rf = 0; rf < 2; ++rf) {
        int row = rowbase + rf * 16 + lr;
        #pragma unroll
        for (int c = 0; c < 5; ++c) {
            const short* p;
            if (c < 2) p = fbf + (size_t)row * FBF_LD + c * 32 + quad * 8;
            else if (c == 2) p = (quad < 2) ? fbf + (size_t)row * FBF_LD + 64 + quad * 8
                                            : agt + (size_t)row * AGT_LD + (quad - 2) * 8;
            else p = agt + (size_t)row * AGT_LD + (c - 3) * 32 + 16 + quad * 8;
            ap[rf][c] = *(const short8*)p;
        }
    }

    f32x4 acc[2][4];
    #pragma unroll
    for (int rf = 0; rf < 2; ++rf)
        #pragma unroll
        for (int n = 0; n < 4; ++n) acc[rf][n] = (f32x4){0.f, 0.f, 0.f, 0.f};

    #pragma unroll
    for (int c = 0; c < 5; ++c) {
        #pragma unroll
        for (int n = 0; n < 4; ++n) {
            if (n < NG) {
                size_t off = (size_t)((ng0 + n) * 16 + lr) * KP1 + c * 32 + quad * 8;
                short8 wh = *(const short8*)(Wthi + off);
                short8 wl = *(const short8*)(Wtlo + off);
                #pragma unroll
                for (int rf = 0; rf < 2; ++rf) {
                    acc[rf][n] = __builtin_amdgcn_mfma_f32_16x16x32_bf16(ap[rf][c], wh, acc[rf][n], 0, 0, 0);
                    acc[rf][n] = __builtin_amdgcn_mfma_f32_16x16x32_bf16(ap[rf][c], wl, acc[rf][n], 0, 0, 0);
                }
            }
        }
    }

    #pragma unroll
    for (int rf = 0; rf < 2; ++rf) {
        #pragma unroll
        for (int n = 0; n < 4; ++n) {
            if (n < NG) {
                int col = (ng0 + n) * 16 + lr;             // 0..111
                float bv = (col < HID) ? bias[col] : 0.f;
                #pragma unroll
                for (int r = 0; r < 4; ++r) {
                    int row = rowbase + rf * 16 + quad * 4 + r;
                    if (row < N_NODES) {
                        unsigned char enc = 0;
                        if (col < HID) enc = enc_fp8_1(fmaxf(acc[rf][n][r] + bv, 0.f));
                        h1c8[(size_t)row * H1C8_LD + col] = enc;
                    }
                }
            }
        }
        if (nh == 1) {  // zero cols 112..127 (complete 128B rows)
            #pragma unroll
            for (int r = 0; r < 4; ++r) {
                int row = rowbase + rf * 16 + quad * 4 + r;
                if (row < N_NODES) h1c8[(size_t)row * H1C8_LD + 112 + lr] = 0;
            }
        }
    }
}

// ---------------- mfma2: h2 = relu([h1c8|agt2] @ Wt2^T + b2) -> bf16 [N][100] + partial aw ----------------
// 2-way n-split as mfma1; partial sigmoid-dot stored per-half in awp[nh*N_NODES + row].

__global__ __launch_bounds__(128) void k_mfma2(
    const unsigned char* __restrict__ h1c8, const short* __restrict__ agt2,
    const short* __restrict__ Wthi, const short* __restrict__ Wtlo,
    const float* __restrict__ bias, const float* __restrict__ w_atom,
    short* __restrict__ h2c, float* __restrict__ awp) {
    int t = threadIdx.x;
    int nh = blockIdx.x & 1, rb = blockIdx.x >> 1;
    const int NG = nh ? 3 : 4;
    const int ng0 = nh ? 4 : 0;
    int wid = t >> 6, lane = t & 63;
    int quad = lane >> 4, lr = lane & 15;
    int rowbase = rb * 64 + wid * 32;

    short8 ap[2][7];
    #pragma unroll
    for (int rf = 0; rf < 2; ++rf) {
        int row = rowbase + rf * 16 + lr;
        const unsigned char* hr = h1c8 + (size_t)row * H1C8_LD;
        const short* ar = agt2 + (size_t)row * AGT2_LD;
        #pragma unroll
        for (int c = 0; c < 7; ++c) {
            if (c < 3) {
                ap[rf][c] = dec8bf(*(const uint2*)(hr + c * 32 + quad * 8));
            } else if (c == 3) {
                if (quad < 2) ap[rf][c] = dec8bf(*(const uint2*)(hr + 96 + quad * 8));
                else ap[rf][c] = *(const short8*)(ar + (quad - 2) * 8);
            } else {
                ap[rf][c] = *(const short8*)(ar + (c - 4) * 32 + 16 + quad * 8);
            }
        }
    }

    f32x4 acc[2][4];
    #pragma unroll
    for (int rf = 0; rf < 2; ++rf)
        #pragma unroll
        for (int n = 0; n < 4; ++n) acc[rf][n] = (f32x4){0.f, 0.f, 0.f, 0.f};

    #pragma unroll
    for (int c = 0; c < 7; ++c) {
        #pragma unroll
        for (int n = 0; n < 4; ++n) {
            if (n < NG) {
                size_t off = (size_t)((ng0 + n) * 16 + lr) * KP2 + c * 32 + quad * 8;
                short8 wh = *(const short8*)(Wthi + off);
                short8 wl = *(const short8*)(Wtlo + off);
                #pragma unroll
                for (int rf = 0; rf < 2; ++rf) {
                    acc[rf][n] = __builtin_amdgcn_mfma_f32_16x16x32_bf16(ap[rf][c], wh, acc[rf][n], 0, 0, 0);
                    acc[rf][n] = __builtin_amdgcn_mfma_f32_16x16x32_bf16(ap[rf][c], wl, acc[rf][n], 0, 0, 0);
                }
            }
        }
    }

    #pragma unroll
    for (int rf = 0; rf < 2; ++rf) {
        float dotr0 = 0.f, dotr1 = 0.f, dotr2 = 0.f, dotr3 = 0.f;
        #pragma unroll
        for (int n = 0; n < 4; ++n) {
            if (n < NG) {
                int col = (ng0 + n) * 16 + lr;
                if (col < HID) {
                    float bv = bias[col];
                    float wa = w_atom[col];
                    #pragma unroll
                    for (int r = 0; r < 4; ++r) {
                        int row = rowbase + rf * 16 + quad * 4 + r;
                        if (row < N_NODES) {
                            float v = fmaxf(acc[rf][n][r] + bv, 0.f);
                            h2c[(size_t)row * H2_LD + col] = (short)f2bf(v);
                            float dv = v * wa;
                            if (r == 0) dotr0 += dv;
                            else if (r == 1) dotr1 += dv;
                            else if (r == 2) dotr2 += dv;
                            else dotr3 += dv;
                        }
                    }
                }
            }
        }
        #pragma unroll
        for (int off = 1; off < 16; off <<= 1) {
            dotr0 += __shfl_xor(dotr0, off, 64);
            dotr1 += __shfl_xor(dotr1, off, 64);
            dotr2 += __shfl_xor(dotr2, off, 64);
            dotr3 += __shfl_xor(dotr3, off, 64);
        }
        if (lr == 0) {
            int row0 = rowbase + rf * 16 + quad * 4;
            float d[4] = {dotr0, dotr1, dotr2, dotr3};
            #pragma unroll
            for (int r = 0; r < 4; ++r) {
                int row = row0 + r;
                if (row < N_NODES) awp[(size_t)nh * N_NODES + row] = d[r];
            }
        }
    }
}

// ---------------- Collapsed predictor head: w_eff[200], b_eff ----------------

__global__ void k_weff(const float* __restrict__ Wp1, const float* __restrict__ bp1,
                       const float* __restrict__ Wp2, const float* __restrict__ bp2,
                       float* __restrict__ weff) {
    int t = threadIdx.x;
    if (t < 200) {
        float s = 0.f;
        for (int k = 0; k < 64; ++k) s += Wp1[t * 64 + k] * Wp2[k];
        weff[t] = s;
    } else if (t == 200) {
        float s = bp2[0];
        for (int k = 0; k < 64; ++k) s += bp1[k] * Wp2[k];
        weff[200] = s;
    }
}

// ---------------- Readout: per-graph weighted sum + max (aw from partials), fused head ----------------

__global__ __launch_bounds__(256) void k_readout(
    const unsigned short* __restrict__ h2c, const float* __restrict__ awp,
    const int* __restrict__ graph_ids, const float* __restrict__ weff,
    const float* __restrict__ b_atom, float* __restrict__ out) {
    int g = blockIdx.x;
    int t = threadIdx.x, lane = t & 63, w = t >> 6;

    int s_, e_;
    {
        int l = 0, r = N_NODES;
        while (l < r) { int m = (l + r) >> 1; if (graph_ids[m] < g) l = m + 1; else r = m; }
        s_ = l;
        l = s_; r = N_NODES;
        while (l < r) { int m = (l + r) >> 1; if (graph_ids[m] < g + 1) l = m + 1; else r = m; }
        e_ = l;
    }

    float ba = b_atom[0];
    float sum0 = 0.f, sum1 = 0.f, mx0 = 0.f, mx1 = 0.f;  // h >= 0 (relu)
    for (int i = s_ + w; i < e_; i += 4) {
        float wt = 1.f / (1.f + __expf(-(awp[i] + awp[N_NODES + i] + ba)));
        if (lane < 50) {
            unsigned wv = *(const unsigned*)(h2c + (size_t)i * H2_LD + 2 * lane);
            float v0 = blo(wv), v1 = bhi(wv);
            sum0 += v0 * wt;
            sum1 += v1 * wt;
            mx0 = fmaxf(mx0, v0);
            mx1 = fmaxf(mx1, v1);
        }
    }

    __shared__ float ssum[4][HID];
    __shared__ float smx[4][HID];
    if (lane < 50) {
        ssum[w][2 * lane] = sum0;
        ssum[w][2 * lane + 1] = sum1;
        smx[w][2 * lane] = mx0;
        smx[w][2 * lane + 1] = mx1;
    }
    __syncthreads();

    float contrib = 0.f;
    if (t < HID) {
        float sumf = ssum[0][t] + ssum[1][t] + ssum[2][t] + ssum[3][t];
        float mxf = fmaxf(fmaxf(smx[0][t], smx[1][t]), fmaxf(smx[2][t], smx[3][t]));
        contrib = sumf * weff[t] + mxf * weff[HID + t];
    }
    #pragma unroll
    for (int off = 32; off; off >>= 1) contrib += __shfl_xor(contrib, off, 64);
    __shared__ float red[4];
    if (lane == 0) red[w] = contrib;
    __syncthreads();
    if (t == 0) out[g] = red[0] + red[1] + red[2] + red[3] + weff[200];
}

// ---------------- launch ----------------

extern "C" void kernel_launch(void* const* d_in, const int* in_sizes, int n_in,
                              void* d_out, int out_size, void* d_ws, size_t ws_size,
                              hipStream_t stream) {
    const float* node_feats = (const float*)d_in[0];
    const int* src = (const int*)d_in[1];
    const int* dst = (const int*)d_in[2];
    const int* gid = (const int*)d_in[3];
    const float* Ws1 = (const float*)d_in[5];
    const float* Wn1 = (const float*)d_in[6];
    const float* b1 = (const float*)d_in[7];
    const float* Ws2 = (const float*)d_in[8];
    const float* Wn2 = (const float*)d_in[9];
    const float* b2 = (const float*)d_in[10];
    const float* w_atom = (const float*)d_in[11];
    const float* b_atom = (const float*)d_in[12];
    const float* Wp1 = (const float*)d_in[13];
    const float* bp1 = (const float*)d_in[14];
    const float* Wp2 = (const float*)d_in[15];
    const float* bp2 = (const float*)d_in[16];
    float* out = (float*)d_out;

    char* ws = (char*)d_ws;
    size_t off = 0;
    auto alloc = [&](size_t bytes) -> void* {
        void* p = (void*)(ws + off);
        off += (bytes + 255) & ~(size_t)255;
        return p;
    };
    int2* rp2 = (int2*)alloc((size_t)N_NODES * sizeof(int2));
    int* bucket_fill = (int*)alloc(NB * sizeof(int));
    int* csr = (int*)alloc((size_t)NB * BKCAP * sizeof(int));                 // 12.8 MB
    unsigned* bbuf = (unsigned*)alloc((size_t)NB * BKCAP * sizeof(unsigned)); // 12.8 MB
    short* fbf = (short*)alloc((size_t)(N_PAD + 1) * FBF_LD * sizeof(short)); // 16 MB
    unsigned char* f8t = (unsigned char*)alloc((size_t)(N_PAD + 1) * F8T_LD); // 8 MB
    short* agt = (short*)alloc((size_t)N_PAD * AGT_LD * sizeof(short));       // 16 MB
    short* agt2 = (short*)alloc((size_t)N_PAD * AGT2_LD * sizeof(short));     // 22.4 MB
    unsigned char* h1c8 = (unsigned char*)alloc((size_t)(N_NODES + 1) * H1C8_LD); // 12.8 MB
    short* h2c = (short*)alloc((size_t)N_NODES * H2_LD * sizeof(short));      // 20 MB
    float* awp = (float*)alloc((size_t)2 * N_NODES * sizeof(float));          // 0.8 MB
    short* Wt1hi = (short*)alloc(112 * KP1 * sizeof(short));
    short* Wt1lo = (short*)alloc(112 * KP1 * sizeof(short));
    short* Wt2hi = (short*)alloc(112 * KP2 * sizeof(short));
    short* Wt2lo = (short*)alloc(112 * KP2 * sizeof(short));
    float* weff = (float*)alloc(256 * sizeof(float));

    hipMemsetAsync(bucket_fill, 0, NB * sizeof(int), stream);

    k_bin<<<NBB, 256, 0, stream>>>(src, dst, bucket_fill, bbuf);
    k_scatter<<<NB, 256, 0, stream>>>(bbuf, bucket_fill, rp2, csr);

    k_feats<<<((N_NODES + 1) * (F8T_LD / 4) + 255) / 256, 256, 0, stream>>>(
        node_feats, fbf, (unsigned*)f8t, (unsigned*)h1c8);
    k_wconv<KP1, F_IN, 80><<<(112 * KP1 + 255) / 256, 256, 0, stream>>>(Ws1, Wn1, Wt1hi, Wt1lo);
    k_wconv<KP2, HID, 112><<<(112 * KP2 + 255) / 256, 256, 0, stream>>>(Ws2, Wn2, Wt2hi, Wt2lo);

    k_prep1<<<(N_NODES + 3) / 4, 256, 0, stream>>>(f8t, rp2, csr, agt);
    k_mfma1<<<(N_PAD / 64) * 2, 128, 0, stream>>>(fbf, agt, Wt1hi, Wt1lo, b1, h1c8);
    k_prep2<<<(N_NODES + 3) / 4, 256, 0, stream>>>(h1c8, rp2, csr, agt2);
    k_mfma2<<<(N_PAD / 64) * 2, 128, 0, stream>>>(h1c8, agt2, Wt2hi, Wt2lo, b2, w_atom, h2c, awp);

    k_weff<<<1, 256, 0, stream>>>(Wp1, bp1, Wp2, bp2, weff);
    k_readout<<<N_GRAPHS, 256, 0, stream>>>((const unsigned short*)h2c, awp, gid, weff, b_atom, out);
}